// Round 1
// baseline (167.558 us; speedup 1.0000x reference)
//
#include <hip/hip_runtime.h>
#include <hip/hip_bf16.h>
#include <stdint.h>

#define SEQ 8192
#define DM 512
#define NSPLIT 4
#define KPB (SEQ / NSPLIT)   // keys per split = 2048
#define KVB 64               // kv block size
#define QB 64                // q rows per attention block (4 waves x 16)

typedef __attribute__((ext_vector_type(8))) short short8v;
typedef __attribute__((ext_vector_type(8))) __bf16 bf16x8;
typedef __attribute__((ext_vector_type(4))) float f32x4;

static __device__ __forceinline__ ushort f2bf(float f) {
  union { float f; uint32_t u; } v; v.f = f;
  uint32_t u = v.u;
  return (ushort)((u + 0x7FFFu + ((u >> 16) & 1u)) >> 16);  // RNE
}

static __device__ __forceinline__ f32x4 mfma16(const ushort* a, const ushort* b, f32x4 c) {
  return __builtin_amdgcn_mfma_f32_16x16x32_bf16(
      *(const bf16x8*)a, *(const bf16x8*)b, c, 0, 0, 0);
}

// ---------------- kernel 1: pack weights+bias to bf16, fold 1/8 into Q ----
__global__ __launch_bounds__(256) void pack_w(
    const float* __restrict__ Wq, const float* __restrict__ bq,
    const float* __restrict__ Wk, const float* __restrict__ bk,
    const float* __restrict__ Wv, const float* __restrict__ bv,
    ushort* __restrict__ Wp, float* __restrict__ biasp) {
  int gid = blockIdx.x * blockDim.x + threadIdx.x;
  if (gid < 192 * 512) {
    int n = gid >> 9;
    float s = 1.0f;
    const float* src; int off;
    if (n < 64)       { src = Wq; off = gid;            s = 0.125f; }
    else if (n < 128) { src = Wk; off = gid - 64 * 512; }
    else              { src = Wv; off = gid - 128 * 512; }
    Wp[gid] = f2bf(src[off] * s);
  }
  if (gid < 192) {
    float s = 1.0f; const float* src; int off = gid;
    if (gid < 64)       { src = bq; s = 0.125f; }
    else if (gid < 128) { src = bk; off = gid - 64; }
    else                { src = bv; off = gid - 128; }
    biasp[gid] = src[off] * s;
  }
}

// ---------------- kernel 2: QKV projection, M-tile 16, bf16 MFMA ----------
// Q[m,n] = sum_k x[m,k] * Wp[n,k]  (both K-contiguous -> B^T GEMM)
__global__ __launch_bounds__(256) void qkv_proj(
    const float* __restrict__ x, const ushort* __restrict__ Wp,
    const float* __restrict__ biasp,
    ushort* __restrict__ Qb, ushort* __restrict__ Kb, ushort* __restrict__ Vb) {
  __shared__ ushort Alds[16][40];   // stride 40 shorts = 80B (16B aligned rows)
  __shared__ ushort Wlds[192][40];
  int t = threadIdx.x;
  int w = t >> 6, l = t & 63;
  int m0 = blockIdx.x * 16;
  int cb = 48 * w;                  // each wave: 3 N-tiles (48 output cols)
  f32x4 acc[3];
  f32x4 zero = {0.f, 0.f, 0.f, 0.f};
  #pragma unroll
  for (int i = 0; i < 3; i++) acc[i] = zero;

  int arow = t >> 4, akq = (t & 15) * 2;  // A staging: 16x32 fp32, 2 per thread
  for (int k0 = 0; k0 < DM; k0 += 32) {
    float2 av = *(const float2*)&x[(m0 + arow) * DM + k0 + akq];
    ushort2 ab; ab.x = f2bf(av.x); ab.y = f2bf(av.y);
    *(ushort2*)&Alds[arow][akq] = ab;
    #pragma unroll
    for (int c = 0; c < 3; c++) {          // W staging: 192x32 bf16
      int idx = t + 256 * c;
      int wrow = idx >> 2, wk = (idx & 3) * 8;
      int4 wv = *(const int4*)&Wp[wrow * DM + k0 + wk];
      *(int4*)&Wlds[wrow][wk] = wv;
    }
    __syncthreads();
    const ushort* ap = &Alds[l & 15][(l >> 4) * 8];
    #pragma unroll
    for (int nt = 0; nt < 3; nt++) {
      acc[nt] = mfma16(ap, &Wlds[cb + nt * 16 + (l & 15)][(l >> 4) * 8], acc[nt]);
    }
    __syncthreads();
  }
  #pragma unroll
  for (int nt = 0; nt < 3; nt++) {
    int col = cb + nt * 16 + (l & 15);
    float bias = biasp[col];
    ushort* dst = (col < 64) ? Qb : (col < 128) ? Kb : Vb;
    int cc = col & 63;
    #pragma unroll
    for (int r = 0; r < 4; r++) {
      int row = m0 + (l >> 4) * 4 + r;
      dst[row * 64 + cc] = f2bf(acc[nt][r] + bias);
    }
  }
}

// ---------------- kernel 3: flash attention, 4-way KV split ---------------
// block: 4 waves, each wave owns 16 q-rows; KV blocks of 64, K & V^T in LDS.
__global__ __launch_bounds__(256) void attn(
    const ushort* __restrict__ Qb, const ushort* __restrict__ Kb,
    const ushort* __restrict__ Vb,
    float* __restrict__ Opart, float* __restrict__ mpart, float* __restrict__ lpart) {
  __shared__ ushort Klds[KVB][72];       // [k][dk], stride 144B (16B-aligned)
  __shared__ ushort VTlds[64][72];       // [d][k]
  __shared__ ushort Plds[4][16][72];     // per-wave [q][k]
  int t = threadIdx.x;
  int w = t >> 6, l = t & 63;
  int qb0 = (blockIdx.x >> 2) * QB;
  int split = blockIdx.x & 3;
  int qrow = qb0 + 16 * w;

  // Q fragments (A-operand): a[i] = Q[l&15][8*(l>>4)+i + 32*s], held in regs
  short8v qf[2];
  #pragma unroll
  for (int s = 0; s < 2; s++)
    qf[s] = *(const short8v*)&Qb[(qrow + (l & 15)) * 64 + 32 * s + (l >> 4) * 8];

  float m[4], lsum[4];
  f32x4 o[4];
  f32x4 zero = {0.f, 0.f, 0.f, 0.f};
  #pragma unroll
  for (int r = 0; r < 4; r++) { m[r] = -1e30f; lsum[r] = 0.f; }
  #pragma unroll
  for (int dt = 0; dt < 4; dt++) o[dt] = zero;

  int ks0 = split * KPB;
  for (int it = 0; it < KPB / KVB; it++) {
    int kbase = ks0 + it * KVB;
    { // stage K (row-major) and V (transposed)
      int kr = t >> 2, dk0 = (t & 3) * 16;
      int4 v0 = *(const int4*)&Kb[(kbase + kr) * 64 + dk0];
      int4 v1 = *(const int4*)&Kb[(kbase + kr) * 64 + dk0 + 8];
      *(int4*)&Klds[kr][dk0] = v0;
      *(int4*)&Klds[kr][dk0 + 8] = v1;
      #pragma unroll
      for (int c = 0; c < 2; c++) {
        int idx = t + 256 * c;
        int vr = idx >> 3, vd0 = (idx & 7) * 8;
        union { int4 v; ushort u[8]; } uv;
        uv.v = *(const int4*)&Vb[(kbase + vr) * 64 + vd0];
        #pragma unroll
        for (int i = 0; i < 8; i++) VTlds[vd0 + i][vr] = uv.u[i];
      }
    }
    __syncthreads();

    // S = Q K^T : C-layout S[q=(l>>4)*4+r][k = 16*kt + (l&15)]
    f32x4 st[4];
    #pragma unroll
    for (int kt = 0; kt < 4; kt++) {
      st[kt] = zero;
      #pragma unroll
      for (int s = 0; s < 2; s++)
        st[kt] = __builtin_amdgcn_mfma_f32_16x16x32_bf16(
            *(const bf16x8*)&qf[s],
            *(const bf16x8*)&Klds[kt * 16 + (l & 15)][32 * s + (l >> 4) * 8],
            st[kt], 0, 0, 0);
    }

    // online softmax (row-max over lane&15 dim x 4 tiles)
    float tm[4];
    #pragma unroll
    for (int r = 0; r < 4; r++)
      tm[r] = fmaxf(fmaxf(st[0][r], st[1][r]), fmaxf(st[2][r], st[3][r]));
    #pragma unroll
    for (int d = 1; d < 16; d <<= 1) {
      #pragma unroll
      for (int r = 0; r < 4; r++)
        tm[r] = fmaxf(tm[r], __shfl_xor(tm[r], d, 64));
    }
    float cfac[4];
    #pragma unroll
    for (int r = 0; r < 4; r++) {
      float mn = fmaxf(m[r], tm[r]);
      cfac[r] = __expf(m[r] - mn);
      m[r] = mn;
    }
    float pexp[4][4];
    #pragma unroll
    for (int kt = 0; kt < 4; kt++)
      #pragma unroll
      for (int r = 0; r < 4; r++)
        pexp[kt][r] = __expf(st[kt][r] - m[r]);
    #pragma unroll
    for (int r = 0; r < 4; r++) {
      float ps = (pexp[0][r] + pexp[1][r]) + (pexp[2][r] + pexp[3][r]);
      lsum[r] = lsum[r] * cfac[r] + ps;   // cross-lane reduce deferred to end
    }
    #pragma unroll
    for (int dt = 0; dt < 4; dt++)
      #pragma unroll
      for (int r = 0; r < 4; r++)
        o[dt][r] *= cfac[r];

    // P (C-layout) -> LDS [q][k] so PV can read it in A-layout
    #pragma unroll
    for (int kt = 0; kt < 4; kt++)
      #pragma unroll
      for (int r = 0; r < 4; r++)
        Plds[w][4 * (l >> 4) + r][kt * 16 + (l & 15)] = f2bf(pexp[kt][r]);

    // O += P V : A = P from Plds, B = V from VTlds (V[k][d] = VT[d][k])
    #pragma unroll
    for (int s = 0; s < 2; s++) {
      const ushort* pa = &Plds[w][l & 15][32 * s + (l >> 4) * 8];
      #pragma unroll
      for (int dt = 0; dt < 4; dt++)
        o[dt] = mfma16(pa, &VTlds[dt * 16 + (l & 15)][32 * s + (l >> 4) * 8], o[dt]);
    }
    __syncthreads();
  }

  // reduce l across the 16-lane group
  #pragma unroll
  for (int d = 1; d < 16; d <<= 1) {
    #pragma unroll
    for (int r = 0; r < 4; r++)
      lsum[r] += __shfl_xor(lsum[r], d, 64);
  }
  float* Op = Opart + (size_t)split * SEQ * 64;
  #pragma unroll
  for (int dt = 0; dt < 4; dt++)
    #pragma unroll
    for (int r = 0; r < 4; r++) {
      int row = qrow + (l >> 4) * 4 + r;
      Op[row * 64 + dt * 16 + (l & 15)] = o[dt][r];
    }
  if ((l & 15) == 0) {
    #pragma unroll
    for (int r = 0; r < 4; r++) {
      int row = qrow + (l >> 4) * 4 + r;
      mpart[split * SEQ + row] = m[r];
      lpart[split * SEQ + row] = lsum[r];
    }
  }
}

// ---------------- kernel 4: combine the 4 KV-split partials ---------------
__global__ __launch_bounds__(256) void combine(
    const float* __restrict__ Opart, const float* __restrict__ mpart,
    const float* __restrict__ lpart, float* __restrict__ out) {
  int gid = blockIdx.x * blockDim.x + threadIdx.x;
  int q = gid >> 6;
  float mm = fmaxf(fmaxf(mpart[q], mpart[SEQ + q]),
                   fmaxf(mpart[2 * SEQ + q], mpart[3 * SEQ + q]));
  float num = 0.f, den = 0.f;
  #pragma unroll
  for (int s = 0; s < NSPLIT; s++) {
    float wgt = __expf(mpart[s * SEQ + q] - mm);
    num += wgt * Opart[(size_t)s * SEQ * 64 + gid];
    den += wgt * lpart[s * SEQ + q];
  }
  out[gid] = num / den;
}

extern "C" void kernel_launch(void* const* d_in, const int* in_sizes, int n_in,
                              void* d_out, int out_size, void* d_ws, size_t ws_size,
                              hipStream_t stream) {
  const float* x  = (const float*)d_in[0];
  const float* Wq = (const float*)d_in[1];
  const float* bq = (const float*)d_in[2];
  const float* Wk = (const float*)d_in[3];
  const float* bk = (const float*)d_in[4];
  const float* Wv = (const float*)d_in[5];
  const float* bv = (const float*)d_in[6];
  float* out = (float*)d_out;

  size_t off = 0;
  auto alloc = [&](size_t bytes) -> void* {
    void* p = (char*)d_ws + off;
    off += (bytes + 255) & ~(size_t)255;
    return p;
  };
  ushort* Wp    = (ushort*)alloc(192 * 512 * 2);
  float*  biasp = (float*) alloc(192 * 4);
  ushort* Qb    = (ushort*)alloc((size_t)SEQ * 64 * 2);
  ushort* Kb    = (ushort*)alloc((size_t)SEQ * 64 * 2);
  ushort* Vb    = (ushort*)alloc((size_t)SEQ * 64 * 2);
  float*  Opart = (float*) alloc((size_t)NSPLIT * SEQ * 64 * 4);
  float*  mpart = (float*) alloc((size_t)NSPLIT * SEQ * 4);
  float*  lpart = (float*) alloc((size_t)NSPLIT * SEQ * 4);

  pack_w<<<(192 * 512 + 255) / 256, 256, 0, stream>>>(Wq, bq, Wk, bk, Wv, bv, Wp, biasp);
  qkv_proj<<<SEQ / 16, 256, 0, stream>>>(x, Wp, biasp, Qb, Kb, Vb);
  attn<<<(SEQ / QB) * NSPLIT, 256, 0, stream>>>(Qb, Kb, Vb, Opart, mpart, lpart);
  combine<<<SEQ * 64 / 256, 256, 0, stream>>>(Opart, mpart, lpart, out);
}

// Round 4
// 141.929 us; speedup vs baseline: 1.1806x; 1.1806x over previous
//
#include <hip/hip_runtime.h>
#include <hip/hip_bf16.h>
#include <stdint.h>

#define SEQ 8192
#define DM 512
#define NSPLIT 8
#define KPB (SEQ / NSPLIT)   // keys per split = 1024
#define KVB 64               // kv block size
#define QB 128               // q rows per attention block (8 waves x 16)

typedef __attribute__((ext_vector_type(8))) short short8v;
typedef __attribute__((ext_vector_type(8))) __bf16 bf16x8;
typedef __attribute__((ext_vector_type(4))) float f32x4;

static __device__ __forceinline__ ushort f2bf(float f) {
  union { float f; uint32_t u; } v; v.f = f;
  uint32_t u = v.u;
  return (ushort)((u + 0x7FFFu + ((u >> 16) & 1u)) >> 16);  // RNE
}

static __device__ __forceinline__ f32x4 mfma16(const ushort* a, const ushort* b, f32x4 c) {
  return __builtin_amdgcn_mfma_f32_16x16x32_bf16(
      *(const bf16x8*)a, *(const bf16x8*)b, c, 0, 0, 0);
}

// ---------------- kernel 1: pack weights+bias to bf16 ---------------------
// Fold (1/8)*log2(e) into Wq/bq so scores are in log2 domain -> exp2 softmax.
__global__ __launch_bounds__(256) void pack_w(
    const float* __restrict__ Wq, const float* __restrict__ bq,
    const float* __restrict__ Wk, const float* __restrict__ bk,
    const float* __restrict__ Wv, const float* __restrict__ bv,
    ushort* __restrict__ Wp, float* __restrict__ biasp) {
  const float QS = 0.125f * 1.44269504088896f;
  int gid = blockIdx.x * blockDim.x + threadIdx.x;
  if (gid < 192 * 512) {
    int n = gid >> 9;
    float s = 1.0f;
    const float* src; int off = gid;
    if (n < 64)       { src = Wq; s = QS; }
    else if (n < 128) { src = Wk; off = gid - 64 * 512; }
    else              { src = Wv; off = gid - 128 * 512; }
    Wp[gid] = f2bf(src[off] * s);
  }
  if (gid < 192) {
    float s = 1.0f; const float* src; int off = gid;
    if (gid < 64)       { src = bq; s = QS; }
    else if (gid < 128) { src = bk; off = gid - 64; }
    else                { src = bv; off = gid - 128; }
    biasp[gid] = src[off] * s;
  }
}

// ---------------- kernel 2: QKV projection, BM=32 BK=128, 8 waves ---------
// out[m,n] = sum_k x[m,k] * Wp[n,k]  (both K-contiguous -> B^T GEMM)
__global__ __launch_bounds__(512) void qkv_proj(
    const float* __restrict__ x, const ushort* __restrict__ Wp,
    const float* __restrict__ biasp,
    ushort* __restrict__ Qb, ushort* __restrict__ Kb, ushort* __restrict__ Vb) {
  __shared__ ushort Alds[32][136];   // 136 shorts = 272B rows (16B aligned)
  __shared__ ushort Wlds[192][136];
  int t = threadIdx.x;
  int w = t >> 6, l = t & 63;
  int g = l >> 4, q16 = l & 15;
  int m0 = blockIdx.x * 32;
  int mrow = 16 * (w & 1);           // wave's 16-row half
  int cb = 48 * (w >> 1);            // wave's 48-col group
  f32x4 acc[3];
  f32x4 zero = {0.f, 0.f, 0.f, 0.f};
  #pragma unroll
  for (int i = 0; i < 3; i++) acc[i] = zero;

  int arow = t >> 4, acol = (t & 15) * 8;   // A staging: 8 fp32 per thread
  for (int k0 = 0; k0 < DM; k0 += 128) {
    {
      float4 a0 = *(const float4*)&x[(size_t)(m0 + arow) * DM + k0 + acol];
      float4 a1 = *(const float4*)&x[(size_t)(m0 + arow) * DM + k0 + acol + 4];
      union { int4 v; ushort u[8]; } ab;
      ab.u[0] = f2bf(a0.x); ab.u[1] = f2bf(a0.y); ab.u[2] = f2bf(a0.z); ab.u[3] = f2bf(a0.w);
      ab.u[4] = f2bf(a1.x); ab.u[5] = f2bf(a1.y); ab.u[6] = f2bf(a1.z); ab.u[7] = f2bf(a1.w);
      *(int4*)&Alds[arow][acol] = ab.v;
      #pragma unroll
      for (int i = 0; i < 6; i++) {          // W staging: 192x128 bf16
        int c = t + 512 * i;
        int wrow = c >> 4, wcol = (c & 15) * 8;
        *(int4*)&Wlds[wrow][wcol] = *(const int4*)&Wp[(size_t)wrow * DM + k0 + wcol];
      }
    }
    __syncthreads();
    #pragma unroll
    for (int s = 0; s < 4; s++) {
      const ushort* ap = &Alds[mrow + q16][32 * s + 8 * g];
      #pragma unroll
      for (int nt = 0; nt < 3; nt++)
        acc[nt] = mfma16(ap, &Wlds[cb + nt * 16 + q16][32 * s + 8 * g], acc[nt]);
    }
    __syncthreads();
  }
  #pragma unroll
  for (int nt = 0; nt < 3; nt++) {
    int col = cb + nt * 16 + q16;
    float bias = biasp[col];
    ushort* dst = (col < 64) ? Qb : (col < 128) ? Kb : Vb;
    int cc = col & 63;
    #pragma unroll
    for (int r = 0; r < 4; r++) {
      int row = m0 + mrow + 4 * g + r;
      dst[(size_t)row * 64 + cc] = f2bf(acc[nt][r] + bias);
    }
  }
}

// ---------------- kernel 3: V -> V^T (once), XOR-swizzled LDS tile --------
__global__ __launch_bounds__(256) void vtrans(
    const ushort* __restrict__ Vb, ushort* __restrict__ VTb) {
  __shared__ ushort T[64][72];
  int t = threadIdx.x;
  int kb0 = blockIdx.x * 64;
  #pragma unroll
  for (int i = 0; i < 2; i++) {
    int c = t + 256 * i;               // 0..511
    int row = c >> 3;                  // 0..63 (k)
    int col0 = (c & 7) * 8;            // 0..56 (d)
    int sw = ((row >> 3) & 7) * 8;     // XOR swizzle keeps 16B alignment
    *(int4*)&T[row][col0 ^ sw] = *(const int4*)&Vb[(size_t)(kb0 + row) * 64 + col0];
  }
  __syncthreads();
  #pragma unroll
  for (int i = 0; i < 2; i++) {
    int c = t + 256 * i;               // 0..511
    int d = c >> 3;                    // 0..63
    int k0 = (c & 7) * 8;              // 0..56
    union { int4 v; ushort u[8]; } uv;
    #pragma unroll
    for (int j = 0; j < 8; j++) {
      int row = k0 + j;
      uv.u[j] = T[row][d ^ (((row >> 3) & 7) * 8)];
    }
    *(int4*)&VTb[(size_t)d * SEQ + kb0 + k0] = uv.v;
  }
}

// ---------------- kernel 4: flash attention, 8-way KV split ---------------
// 8 waves/block, each wave owns 16 q-rows; KV blocks of 64; K and V^T staged
// from global (V^T pre-transposed). Softmax in exp2 domain with defer-max.
__global__ __launch_bounds__(512) void attn(
    const ushort* __restrict__ Qb, const ushort* __restrict__ Kb,
    const ushort* __restrict__ VTb,
    float* __restrict__ Opart, float* __restrict__ mpart, float* __restrict__ lpart) {
  __shared__ ushort Klds[KVB][72];       // [k][d]
  __shared__ ushort VTlds[64][72];       // [d][k]
  __shared__ ushort Plds[8][16][72];     // per-wave [q][k]
  int t = threadIdx.x;
  int w = t >> 6, l = t & 63;
  int g = l >> 4, q16 = l & 15;
  int qb0 = (blockIdx.x & 63) * QB;
  int split = blockIdx.x >> 6;
  int qrow = qb0 + 16 * w;

  short8v qf[2];
  #pragma unroll
  for (int s = 0; s < 2; s++)
    qf[s] = *(const short8v*)&Qb[(size_t)(qrow + q16) * 64 + 32 * s + 8 * g];

  float m[4], lsum[4];
  f32x4 o[4];
  f32x4 zero = {0.f, 0.f, 0.f, 0.f};
  #pragma unroll
  for (int r = 0; r < 4; r++) { m[r] = -1e30f; lsum[r] = 0.f; }
  #pragma unroll
  for (int dt = 0; dt < 4; dt++) o[dt] = zero;

  int ks0 = split * KPB;
  int krow = t >> 3, d8 = (t & 7) * 8;
  for (int it = 0; it < KPB / KVB; it++) {
    int kbase = ks0 + it * KVB;
    // stage K [64][64] and VT [64][64]: one int4 each per thread
    *(int4*)&Klds[krow][d8]  = *(const int4*)&Kb[(size_t)(kbase + krow) * 64 + d8];
    *(int4*)&VTlds[krow][d8] = *(const int4*)&VTb[(size_t)krow * SEQ + kbase + d8];
    __syncthreads();

    // S = Q K^T : S[q=4g+r][k=16kt+q16]
    f32x4 st[4];
    #pragma unroll
    for (int kt = 0; kt < 4; kt++) {
      st[kt] = zero;
      #pragma unroll
      for (int s = 0; s < 2; s++)
        st[kt] = __builtin_amdgcn_mfma_f32_16x16x32_bf16(
            *(const bf16x8*)&qf[s],
            *(const bf16x8*)&Klds[kt * 16 + q16][32 * s + 8 * g],
            st[kt], 0, 0, 0);
    }

    // online softmax in exp2 domain
    float tm[4];
    #pragma unroll
    for (int r = 0; r < 4; r++)
      tm[r] = fmaxf(fmaxf(st[0][r], st[1][r]), fmaxf(st[2][r], st[3][r]));
    #pragma unroll
    for (int d = 1; d < 16; d <<= 1) {
      #pragma unroll
      for (int r = 0; r < 4; r++)
        tm[r] = fmaxf(tm[r], __shfl_xor(tm[r], d, 64));
    }
    // defer-max: only rescale when the max grew by > 8 (P bounded by 2^8)
    float dmax = tm[0] - m[0];
    #pragma unroll
    for (int r = 1; r < 4; r++) dmax = fmaxf(dmax, tm[r] - m[r]);
    if (!__all(dmax <= 8.0f)) {
      #pragma unroll
      for (int r = 0; r < 4; r++) {
        float mn = fmaxf(m[r], tm[r]);
        float cf = exp2f(m[r] - mn);
        m[r] = mn;
        lsum[r] *= cf;
        #pragma unroll
        for (int dt = 0; dt < 4; dt++) o[dt][r] *= cf;
      }
    }
    float pexp[4][4];
    #pragma unroll
    for (int kt = 0; kt < 4; kt++)
      #pragma unroll
      for (int r = 0; r < 4; r++)
        pexp[kt][r] = exp2f(st[kt][r] - m[r]);
    #pragma unroll
    for (int r = 0; r < 4; r++)
      lsum[r] += (pexp[0][r] + pexp[1][r]) + (pexp[2][r] + pexp[3][r]);

    // P (C-layout) -> LDS [q][k] for the PV A-operand
    #pragma unroll
    for (int kt = 0; kt < 4; kt++)
      #pragma unroll
      for (int r = 0; r < 4; r++)
        Plds[w][4 * g + r][kt * 16 + q16] = f2bf(pexp[kt][r]);

    // O += P V
    #pragma unroll
    for (int s = 0; s < 2; s++) {
      const ushort* pa = &Plds[w][q16][32 * s + 8 * g];
      #pragma unroll
      for (int dt = 0; dt < 4; dt++)
        o[dt] = mfma16(pa, &VTlds[dt * 16 + q16][32 * s + 8 * g], o[dt]);
    }
    __syncthreads();
  }

  // reduce lsum across the 16-lane (k-column) group
  #pragma unroll
  for (int d = 1; d < 16; d <<= 1) {
    #pragma unroll
    for (int r = 0; r < 4; r++)
      lsum[r] += __shfl_xor(lsum[r], d, 64);
  }
  float* Op = Opart + (size_t)split * SEQ * 64;
  #pragma unroll
  for (int dt = 0; dt < 4; dt++)
    #pragma unroll
    for (int r = 0; r < 4; r++) {
      int row = qrow + 4 * g + r;
      Op[(size_t)row * 64 + dt * 16 + q16] = o[dt][r];
    }
  if (q16 == 0) {
    #pragma unroll
    for (int r = 0; r < 4; r++) {
      int row = qrow + 4 * g + r;
      mpart[split * SEQ + row] = m[r];
      lpart[split * SEQ + row] = lsum[r];
    }
  }
}

// ---------------- kernel 5: combine the 8 KV-split partials ---------------
__global__ __launch_bounds__(256) void combine(
    const float* __restrict__ Opart, const float* __restrict__ mpart,
    const float* __restrict__ lpart, float* __restrict__ out) {
  int gid = blockIdx.x * blockDim.x + threadIdx.x;
  int q = gid >> 6;
  float mm = mpart[q];
  #pragma unroll
  for (int s = 1; s < NSPLIT; s++) mm = fmaxf(mm, mpart[s * SEQ + q]);
  float num = 0.f, den = 0.f;
  #pragma unroll
  for (int s = 0; s < NSPLIT; s++) {
    float wgt = exp2f(mpart[s * SEQ + q] - mm);
    num += wgt * Opart[(size_t)s * SEQ * 64 + gid];
    den += wgt * lpart[s * SEQ + q];
  }
  out[gid] = num / den;
}

extern "C" void kernel_launch(void* const* d_in, const int* in_sizes, int n_in,
                              void* d_out, int out_size, void* d_ws, size_t ws_size,
                              hipStream_t stream) {
  const float* x  = (const float*)d_in[0];
  const float* Wq = (const float*)d_in[1];
  const float* bq = (const float*)d_in[2];
  const float* Wk = (const float*)d_in[3];
  const float* bk = (const float*)d_in[4];
  const float* Wv = (const float*)d_in[5];
  const float* bv = (const float*)d_in[6];
  float* out = (float*)d_out;

  size_t off = 0;
  auto alloc = [&](size_t bytes) -> void* {
    void* p = (char*)d_ws + off;
    off += (bytes + 255) & ~(size_t)255;
    return p;
  };
  ushort* Wp    = (ushort*)alloc(192 * 512 * 2);
  float*  biasp = (float*) alloc(192 * 4);
  ushort* Qb    = (ushort*)alloc((size_t)SEQ * 64 * 2);
  ushort* Kb    = (ushort*)alloc((size_t)SEQ * 64 * 2);
  ushort* Vb    = (ushort*)alloc((size_t)SEQ * 64 * 2);
  ushort* VTb   = (ushort*)alloc((size_t)64 * SEQ * 2);
  float*  Opart = (float*) alloc((size_t)NSPLIT * SEQ * 64 * 4);
  float*  mpart = (float*) alloc((size_t)NSPLIT * SEQ * 4);
  float*  lpart = (float*) alloc((size_t)NSPLIT * SEQ * 4);

  pack_w<<<(192 * 512 + 255) / 256, 256, 0, stream>>>(Wq, bq, Wk, bk, Wv, bv, Wp, biasp);
  qkv_proj<<<SEQ / 32, 512, 0, stream>>>(x, Wp, biasp, Qb, Kb, Vb);
  vtrans<<<SEQ / 64, 256, 0, stream>>>(Vb, VTb);
  attn<<<(SEQ / QB) * NSPLIT, 512, 0, stream>>>(Qb, Kb, VTb, Opart, mpart, lpart);
  combine<<<SEQ * 64 / 256, 256, 0, stream>>>(Opart, mpart, lpart, out);
}

// Round 7
// 130.531 us; speedup vs baseline: 1.2837x; 1.0873x over previous
//
#include <hip/hip_runtime.h>
#include <hip/hip_bf16.h>
#include <stdint.h>

#define SEQ 8192
#define DM 512
#define NSPLIT 8
#define KPB (SEQ / NSPLIT)   // 1024 keys per split
#define KVB 64               // kv block size
#define QB 64                // q rows per attention block (4 waves x 16)
#define NIT (KPB / KVB)      // 16 kv-iterations per block

typedef __attribute__((ext_vector_type(8))) short short8v;
typedef __attribute__((ext_vector_type(8))) __bf16 bf16x8;
typedef __attribute__((ext_vector_type(4))) float f32x4;

static __device__ __forceinline__ ushort f2bf(float f) {
  union { float f; uint32_t u; } v; v.f = f;
  uint32_t u = v.u;
  return (ushort)((u + 0x7FFFu + ((u >> 16) & 1u)) >> 16);  // RNE
}

static __device__ __forceinline__ f32x4 mfma16(const ushort* a, const ushort* b, f32x4 c) {
  return __builtin_amdgcn_mfma_f32_16x16x32_bf16(
      *(const bf16x8*)a, *(const bf16x8*)b, c, 0, 0, 0);
}

// ---------------- kernel 1: pack weights+bias to bf16 ---------------------
// Fold (1/8)*log2(e) into Wq/bq so scores are in log2 domain -> exp2 softmax.
__global__ __launch_bounds__(256) void pack_w(
    const float* __restrict__ Wq, const float* __restrict__ bq,
    const float* __restrict__ Wk, const float* __restrict__ bk,
    const float* __restrict__ Wv, const float* __restrict__ bv,
    ushort* __restrict__ Wp, float* __restrict__ biasp) {
  const float QS = 0.125f * 1.44269504088896f;
  int gid = blockIdx.x * blockDim.x + threadIdx.x;
  if (gid < 192 * 512) {
    int n = gid >> 9;
    float s = 1.0f;
    const float* src; int off = gid;
    if (n < 64)       { src = Wq; s = QS; }
    else if (n < 128) { src = Wk; off = gid - 64 * 512; }
    else              { src = Wv; off = gid - 128 * 512; }
    Wp[gid] = f2bf(src[off] * s);
  }
  if (gid < 192) {
    float s = 1.0f; const float* src; int off = gid;
    if (gid < 64)       { src = bq; s = QS; }
    else if (gid < 128) { src = bk; off = gid - 64; }
    else                { src = bv; off = gid - 128; }
    biasp[gid] = src[off] * s;
  }
}

// ---------------- kernel 2: QKV projection + fused V-transpose ------------
// out[m,n] = sum_k x[m,k] * Wp[n,k]. Q,K row-major; V written transposed.
__global__ __launch_bounds__(512) void qkv_proj(
    const float* __restrict__ x, const ushort* __restrict__ Wp,
    const float* __restrict__ biasp,
    ushort* __restrict__ Qb, ushort* __restrict__ Kb, ushort* __restrict__ VTb) {
  __shared__ ushort Alds[32][136];
  __shared__ ushort Wlds[192][136];
  int t = threadIdx.x;
  int w = t >> 6, l = t & 63;
  int g = l >> 4, q16 = l & 15;
  int m0 = blockIdx.x * 32;
  int mrow = 16 * (w & 1);
  int cb = 48 * (w >> 1);
  f32x4 acc[3];
  f32x4 zero = {0.f, 0.f, 0.f, 0.f};
  #pragma unroll
  for (int i = 0; i < 3; i++) acc[i] = zero;

  int arow = t >> 4, acol = (t & 15) * 8;
  for (int k0 = 0; k0 < DM; k0 += 128) {
    {
      float4 a0 = *(const float4*)&x[(size_t)(m0 + arow) * DM + k0 + acol];
      float4 a1 = *(const float4*)&x[(size_t)(m0 + arow) * DM + k0 + acol + 4];
      union { int4 v; ushort u[8]; } ab;
      ab.u[0] = f2bf(a0.x); ab.u[1] = f2bf(a0.y); ab.u[2] = f2bf(a0.z); ab.u[3] = f2bf(a0.w);
      ab.u[4] = f2bf(a1.x); ab.u[5] = f2bf(a1.y); ab.u[6] = f2bf(a1.z); ab.u[7] = f2bf(a1.w);
      *(int4*)&Alds[arow][acol] = ab.v;
      #pragma unroll
      for (int i = 0; i < 6; i++) {
        int c = t + 512 * i;
        int wrow = c >> 4, wcol = (c & 15) * 8;
        *(int4*)&Wlds[wrow][wcol] = *(const int4*)&Wp[(size_t)wrow * DM + k0 + wcol];
      }
    }
    __syncthreads();
    #pragma unroll
    for (int s = 0; s < 4; s++) {
      const ushort* ap = &Alds[mrow + q16][32 * s + 8 * g];
      #pragma unroll
      for (int nt = 0; nt < 3; nt++)
        acc[nt] = mfma16(ap, &Wlds[cb + nt * 16 + q16][32 * s + 8 * g], acc[nt]);
    }
    __syncthreads();
  }
  #pragma unroll
  for (int nt = 0; nt < 3; nt++) {
    int col = cb + nt * 16 + q16;
    float bias = biasp[col];
    if (col < 128) {
      ushort* dst = (col < 64) ? Qb : Kb;
      int cc = col & 63;
      #pragma unroll
      for (int r = 0; r < 4; r++) {
        int row = m0 + mrow + 4 * g + r;
        dst[(size_t)row * 64 + cc] = f2bf(acc[nt][r] + bias);
      }
    } else {
      int cc = col - 128;   // V column -> VT row
      #pragma unroll
      for (int r = 0; r < 4; r++) {
        int row = m0 + mrow + 4 * g + r;
        VTb[(size_t)cc * SEQ + row] = f2bf(acc[nt][r] + bias);
      }
    }
  }
}

// ---------------- kernel 3: flash attention, swapped QK^T -----------------
// 4 waves/block, wave owns 16 q-rows. Swapped-operand MFMA puts a full
// S-row (64 k) in each lane's 16 regs -> scalar online softmax, P written
// via 4x ds_write_b64. 2-phase reg prefetch hides K/VT load latency.
__global__ __launch_bounds__(256, 4) void attn(
    const ushort* __restrict__ Qb, const ushort* __restrict__ Kb,
    const ushort* __restrict__ VTb,
    float* __restrict__ OT, float* __restrict__ mpart, float* __restrict__ lpart) {
  __shared__ ushort Klds[KVB][72];       // [k][d]
  __shared__ ushort VTlds[64][72];       // [d][k]
  __shared__ ushort PT[4][16][72];       // per-wave P[q][k]
  int t = threadIdx.x;
  int w = t >> 6, l = t & 63;
  int g = l >> 4, q16 = l & 15;
  int qb = blockIdx.x & 127;
  int split = blockIdx.x >> 7;
  int qrow = qb * QB + 16 * w;

  // Q fragment (B-operand of swapped QK^T): lane holds Q[q16][8g+j+32s]
  short8v qf[2];
  #pragma unroll
  for (int s = 0; s < 2; s++)
    qf[s] = *(const short8v*)&Qb[(size_t)(qrow + q16) * 64 + 32 * s + 8 * g];

  float m = -1e30f, lsum = 0.f;
  f32x4 o[4];
  f32x4 zero = {0.f, 0.f, 0.f, 0.f};
  #pragma unroll
  for (int dt = 0; dt < 4; dt++) o[dt] = zero;

  int ks0 = split * KPB;
  const int rA = t >> 3, cA = (t & 7) * 8, rB = rA + 32;

  // prefetch tile 0 into regs
  int4 ka, kb2, va, vb2;
  {
    int kb = ks0;
    ka  = *(const int4*)&Kb[(size_t)(kb + rA) * 64 + cA];
    kb2 = *(const int4*)&Kb[(size_t)(kb + rB) * 64 + cA];
    va  = *(const int4*)&VTb[(size_t)rA * SEQ + kb + cA];
    vb2 = *(const int4*)&VTb[(size_t)rB * SEQ + kb + cA];
  }

  for (int it = 0; it < NIT; it++) {
    // write staged regs to LDS (prev-iter reads guarded by loop-end barrier)
    *(int4*)&Klds[rA][cA]  = ka;
    *(int4*)&Klds[rB][cA]  = kb2;
    *(int4*)&VTlds[rA][cA] = va;
    *(int4*)&VTlds[rB][cA] = vb2;
    __syncthreads();
    // issue next tile's loads; they fly under the compute phase
    if (it + 1 < NIT) {
      int kb = ks0 + (it + 1) * KVB;
      ka  = *(const int4*)&Kb[(size_t)(kb + rA) * 64 + cA];
      kb2 = *(const int4*)&Kb[(size_t)(kb + rB) * 64 + cA];
      va  = *(const int4*)&VTb[(size_t)rA * SEQ + kb + cA];
      vb2 = *(const int4*)&VTb[(size_t)rB * SEQ + kb + cA];
    }

    // S^T-free: mfma(A=K, B=Q) -> st[kt] holds S[q16][k=16kt+4g+r]
    f32x4 st[4];
    #pragma unroll
    for (int kt = 0; kt < 4; kt++) {
      st[kt] = zero;
      #pragma unroll
      for (int s = 0; s < 2; s++)
        st[kt] = __builtin_amdgcn_mfma_f32_16x16x32_bf16(
            *(const bf16x8*)&Klds[kt * 16 + q16][32 * s + 8 * g],
            *(const bf16x8*)&qf[s],
            st[kt], 0, 0, 0);
    }

    // scalar online softmax (lane owns one q-row's 16 of 64 k; rest in g-peers)
    float tm = st[0][0];
    #pragma unroll
    for (int kt = 0; kt < 4; kt++)
      #pragma unroll
      for (int r = 0; r < 4; r++) tm = fmaxf(tm, st[kt][r]);
    tm = fmaxf(tm, __shfl_xor(tm, 16, 64));
    tm = fmaxf(tm, __shfl_xor(tm, 32, 64));
    // defer-max: skip rescale while max grew by <= 8 (P bounded by 2^8)
    if (!__all(tm - m <= 8.0f)) {
      float mn = fmaxf(m, tm);
      float cf = exp2f(m - mn);
      m = mn;
      lsum *= cf;
      #pragma unroll
      for (int dt = 0; dt < 4; dt++) o[dt] *= cf;
    }
    float ps = 0.f;
    #pragma unroll
    for (int kt = 0; kt < 4; kt++) {
      float p0 = exp2f(st[kt][0] - m), p1 = exp2f(st[kt][1] - m);
      float p2 = exp2f(st[kt][2] - m), p3 = exp2f(st[kt][3] - m);
      ps += (p0 + p1) + (p2 + p3);
      uint2 pk;
      pk.x = (uint)f2bf(p0) | ((uint)f2bf(p1) << 16);
      pk.y = (uint)f2bf(p2) | ((uint)f2bf(p3) << 16);
      *(uint2*)&PT[w][q16][16 * kt + 4 * g] = pk;   // P[q16][k], k-contiguous
    }
    lsum += ps;

    // O^T += V^T P^T : A = VT from LDS, B = P row-read (b128)
    #pragma unroll
    for (int s = 0; s < 2; s++) {
      bf16x8 pf = *(const bf16x8*)&PT[w][q16][32 * s + 8 * g];
      #pragma unroll
      for (int dt = 0; dt < 4; dt++)
        o[dt] = __builtin_amdgcn_mfma_f32_16x16x32_bf16(
            *(const bf16x8*)&VTlds[dt * 16 + q16][32 * s + 8 * g],
            pf, o[dt], 0, 0, 0);
    }
    __syncthreads();
  }

  // reduce lsum across the 4 g-groups (k-partitions)
  lsum += __shfl_xor(lsum, 16, 64);
  lsum += __shfl_xor(lsum, 32, 64);

  // O^T store: lane holds O[q16][d=16dt+4g+r] -> OT[d][q] coalesced in q16
  float* OTp = OT + (size_t)split * 64 * SEQ;
  #pragma unroll
  for (int dt = 0; dt < 4; dt++)
    #pragma unroll
    for (int r = 0; r < 4; r++)
      OTp[(size_t)(16 * dt + 4 * g + r) * SEQ + qrow + q16] = o[dt][r];
  if (l < 16) {
    mpart[split * SEQ + qrow + l] = m;
    lpart[split * SEQ + qrow + l] = lsum;
  }
}

// ---------------- kernel 4: combine the KV-split partials -----------------
// OT layout [split][d][q]; block owns 64 q-rows x all 64 d.
__global__ __launch_bounds__(256) void combine(
    const float* __restrict__ OT, const float* __restrict__ mpart,
    const float* __restrict__ lpart, float* __restrict__ out) {
  int t = threadIdx.x;
  int q = blockIdx.x * 64 + (t & 63);
  int dof = t >> 6;                      // 0..3, 16 d each
  float mm = -1e30f;
  #pragma unroll
  for (int s = 0; s < NSPLIT; s++) mm = fmaxf(mm, mpart[s * SEQ + q]);
  float ws[NSPLIT], den = 0.f;
  #pragma unroll
  for (int s = 0; s < NSPLIT; s++) {
    ws[s] = exp2f(mpart[s * SEQ + q] - mm);
    den += ws[s] * lpart[s * SEQ + q];
  }
  float rden = 1.0f / den;
  #pragma unroll
  for (int s = 0; s < NSPLIT; s++) ws[s] *= rden;
  #pragma unroll
  for (int k = 0; k < 16; k++) {
    int d = dof * 16 + k;
    float num = 0.f;
    #pragma unroll
    for (int s = 0; s < NSPLIT; s++)
      num += ws[s] * OT[(size_t)s * 64 * SEQ + (size_t)d * SEQ + q];
    out[(size_t)q * 64 + d] = num;
  }
}

extern "C" void kernel_launch(void* const* d_in, const int* in_sizes, int n_in,
                              void* d_out, int out_size, void* d_ws, size_t ws_size,
                              hipStream_t stream) {
  const float* x  = (const float*)d_in[0];
  const float* Wq = (const float*)d_in[1];
  const float* bq = (const float*)d_in[2];
  const float* Wk = (const float*)d_in[3];
  const float* bk = (const float*)d_in[4];
  const float* Wv = (const float*)d_in[5];
  const float* bv = (const float*)d_in[6];
  float* out = (float*)d_out;

  size_t off = 0;
  auto alloc = [&](size_t bytes) -> void* {
    void* p = (char*)d_ws + off;
    off += (bytes + 255) & ~(size_t)255;
    return p;
  };
  ushort* Wp    = (ushort*)alloc(192 * 512 * 2);
  float*  biasp = (float*) alloc(192 * 4);
  ushort* Qb    = (ushort*)alloc((size_t)SEQ * 64 * 2);
  ushort* Kb    = (ushort*)alloc((size_t)SEQ * 64 * 2);
  ushort* VTb   = (ushort*)alloc((size_t)64 * SEQ * 2);
  float*  OT    = (float*) alloc((size_t)NSPLIT * 64 * SEQ * 4);
  float*  mpart = (float*) alloc((size_t)NSPLIT * SEQ * 4);
  float*  lpart = (float*) alloc((size_t)NSPLIT * SEQ * 4);

  pack_w<<<(192 * 512 + 255) / 256, 256, 0, stream>>>(Wq, bq, Wk, bk, Wv, bv, Wp, biasp);
  qkv_proj<<<SEQ / 32, 512, 0, stream>>>(x, Wp, biasp, Qb, Kb, VTb);
  attn<<<(SEQ / QB) * NSPLIT, 256, 0, stream>>>(Qb, Kb, VTb, OT, mpart, lpart);
  combine<<<SEQ / 64, 256, 0, stream>>>(OT, mpart, lpart, out);
}

// Round 14
// 124.316 us; speedup vs baseline: 1.3478x; 1.0500x over previous
//
#include <hip/hip_runtime.h>
#include <hip/hip_bf16.h>
#include <stdint.h>

#define SEQ 8192
#define DM 512
#define NSPLIT 8
#define KPB (SEQ / NSPLIT)   // 1024 keys per split
#define KVB 64               // kv block size
#define QB 128               // q rows per attention block (8 waves x 16)
#define NIT (KPB / KVB)      // 16 kv-iterations per block

typedef __attribute__((ext_vector_type(8))) short short8v;
typedef __attribute__((ext_vector_type(8))) __bf16 bf16x8;
typedef __attribute__((ext_vector_type(4))) float f32x4;

// native convert (compiler fuses pairs into v_cvt_pk_bf16_f32; RNE)
static __device__ __forceinline__ ushort bfh(float f) {
  union { __hip_bfloat16 h; ushort u; } c;
  c.h = __float2bfloat16(f);
  return c.u;
}

static __device__ __forceinline__ f32x4 mfma16(const ushort* a, const ushort* b, f32x4 c) {
  return __builtin_amdgcn_mfma_f32_16x16x32_bf16(
      *(const bf16x8*)a, *(const bf16x8*)b, c, 0, 0, 0);
}

// ---------------- kernel 1: pack weights+bias to bf16 ---------------------
// Fold (1/8)*log2(e) into Wq/bq so scores are in log2 domain -> exp2 softmax.
__global__ __launch_bounds__(256) void pack_w(
    const float* __restrict__ Wq, const float* __restrict__ bq,
    const float* __restrict__ Wk, const float* __restrict__ bk,
    const float* __restrict__ Wv, const float* __restrict__ bv,
    ushort* __restrict__ Wp, float* __restrict__ biasp) {
  const float QS = 0.125f * 1.44269504088896f;
  int gid = blockIdx.x * blockDim.x + threadIdx.x;
  if (gid < 192 * 512) {
    int n = gid >> 9;
    float s = 1.0f;
    const float* src; int off = gid;
    if (n < 64)       { src = Wq; s = QS; }
    else if (n < 128) { src = Wk; off = gid - 64 * 512; }
    else              { src = Wv; off = gid - 128 * 512; }
    Wp[gid] = bfh(src[off] * s);
  }
  if (gid < 192) {
    float s = 1.0f; const float* src; int off = gid;
    if (gid < 64)       { src = bq; s = QS; }
    else if (gid < 128) { src = bk; off = gid - 64; }
    else                { src = bv; off = gid - 128; }
    biasp[gid] = src[off] * s;
  }
}

// ---------------- kernel 2: QKV projection + fused V-transpose ------------
// out[m,n] = sum_k x[m,k] * Wp[n,k]. Q,K row-major; V written transposed.
__global__ __launch_bounds__(512) void qkv_proj(
    const float* __restrict__ x, const ushort* __restrict__ Wp,
    const float* __restrict__ biasp,
    ushort* __restrict__ Qb, ushort* __restrict__ Kb, ushort* __restrict__ VTb) {
  __shared__ ushort Alds[32][136];
  __shared__ ushort Wlds[192][136];
  int t = threadIdx.x;
  int w = t >> 6, l = t & 63;
  int g = l >> 4, q16 = l & 15;
  int m0 = blockIdx.x * 32;
  int mrow = 16 * (w & 1);
  int cb = 48 * (w >> 1);
  f32x4 acc[3];
  f32x4 zero = {0.f, 0.f, 0.f, 0.f};
  #pragma unroll
  for (int i = 0; i < 3; i++) acc[i] = zero;

  int arow = t >> 4, acol = (t & 15) * 8;
  for (int k0 = 0; k0 < DM; k0 += 128) {
    {
      float4 a0 = *(const float4*)&x[(size_t)(m0 + arow) * DM + k0 + acol];
      float4 a1 = *(const float4*)&x[(size_t)(m0 + arow) * DM + k0 + acol + 4];
      union { int4 v; ushort u[8]; } ab;
      ab.u[0] = bfh(a0.x); ab.u[1] = bfh(a0.y); ab.u[2] = bfh(a0.z); ab.u[3] = bfh(a0.w);
      ab.u[4] = bfh(a1.x); ab.u[5] = bfh(a1.y); ab.u[6] = bfh(a1.z); ab.u[7] = bfh(a1.w);
      *(int4*)&Alds[arow][acol] = ab.v;
      #pragma unroll
      for (int i = 0; i < 6; i++) {
        int c = t + 512 * i;
        int wrow = c >> 4, wcol = (c & 15) * 8;
        *(int4*)&Wlds[wrow][wcol] = *(const int4*)&Wp[(size_t)wrow * DM + k0 + wcol];
      }
    }
    __syncthreads();
    #pragma unroll
    for (int s = 0; s < 4; s++) {
      const ushort* ap = &Alds[mrow + q16][32 * s + 8 * g];
      #pragma unroll
      for (int nt = 0; nt < 3; nt++)
        acc[nt] = mfma16(ap, &Wlds[cb + nt * 16 + q16][32 * s + 8 * g], acc[nt]);
    }
    __syncthreads();
  }
  #pragma unroll
  for (int nt = 0; nt < 3; nt++) {
    int col = cb + nt * 16 + q16;
    float bias = biasp[col];
    if (col < 128) {
      ushort* dst = (col < 64) ? Qb : Kb;
      int cc = col & 63;
      #pragma unroll
      for (int r = 0; r < 4; r++) {
        int row = m0 + mrow + 4 * g + r;
        dst[(size_t)row * 64 + cc] = bfh(acc[nt][r] + bias);
      }
    } else {
      int cc = col - 128;   // V column -> VT row
      #pragma unroll
      for (int r = 0; r < 4; r++) {
        int row = m0 + mrow + 4 * g + r;
        VTb[(size_t)cc * SEQ + row] = bfh(acc[nt][r] + bias);
      }
    }
  }
}

// ---------------- kernel 3: flash attention, swapped QK^T, 8 waves --------
// 8 waves/block share one K/VT staging tile (1 int4 each per thread per
// iter); wave owns 16 q-rows. Swapped-operand MFMA -> scalar per-lane
// online softmax. 2-phase reg prefetch hides K/VT load latency.
__global__ __launch_bounds__(512, 4) void attn(
    const ushort* __restrict__ Qb, const ushort* __restrict__ Kb,
    const ushort* __restrict__ VTb,
    float* __restrict__ OT, float* __restrict__ mpart, float* __restrict__ lpart) {
  __shared__ ushort Klds[KVB][72];       // [k][d]
  __shared__ ushort VTlds[64][72];       // [d][k]
  __shared__ ushort PT[8][16][72];       // per-wave P[q][k]
  int t = threadIdx.x;
  int w = t >> 6, l = t & 63;
  int g = l >> 4, q16 = l & 15;
  int qb = blockIdx.x & 63;
  int split = blockIdx.x >> 6;
  int qrow = qb * QB + 16 * w;

  // Q fragment (B-operand of swapped QK^T): lane holds Q[q16][8g+j+32s]
  short8v qf[2];
  #pragma unroll
  for (int s = 0; s < 2; s++)
    qf[s] = *(const short8v*)&Qb[(size_t)(qrow + q16) * 64 + 32 * s + 8 * g];

  float m = -1e30f, lsum = 0.f;
  f32x4 o[4];
  f32x4 zero = {0.f, 0.f, 0.f, 0.f};
  #pragma unroll
  for (int dt = 0; dt < 4; dt++) o[dt] = zero;

  int ks0 = split * KPB;
  const int rA = t >> 3, cA = (t & 7) * 8;   // 512 threads cover 64x64 once

  // strength-reduced global pointers; prefetch tile 0
  const ushort* kp = Kb + (size_t)(ks0 + rA) * 64 + cA;
  const ushort* vp = VTb + (size_t)rA * SEQ + ks0 + cA;
  int4 ka = *(const int4*)kp;
  int4 va = *(const int4*)vp;

  for (int it = 0; it < NIT; it++) {
    *(int4*)&Klds[rA][cA]  = ka;
    *(int4*)&VTlds[rA][cA] = va;
    __syncthreads();
    // issue next tile's loads; they fly under the compute phase
    if (it + 1 < NIT) {
      kp += KVB * 64;
      vp += KVB;
      ka = *(const int4*)kp;
      va = *(const int4*)vp;
    }

    // swapped: mfma(A=K, B=Q) -> st[kt] holds S[q16][k=16kt+4g+r]
    f32x4 st[4];
    #pragma unroll
    for (int kt = 0; kt < 4; kt++) {
      st[kt] = zero;
      #pragma unroll
      for (int s = 0; s < 2; s++)
        st[kt] = __builtin_amdgcn_mfma_f32_16x16x32_bf16(
            *(const bf16x8*)&Klds[kt * 16 + q16][32 * s + 8 * g],
            *(const bf16x8*)&qf[s],
            st[kt], 0, 0, 0);
    }

    // scalar online softmax (lane owns one q-row's 16 of 64 k; rest in g-peers)
    float tm = st[0][0];
    #pragma unroll
    for (int kt = 0; kt < 4; kt++)
      #pragma unroll
      for (int r = 0; r < 4; r++) tm = fmaxf(tm, st[kt][r]);
    tm = fmaxf(tm, __shfl_xor(tm, 16, 64));
    tm = fmaxf(tm, __shfl_xor(tm, 32, 64));
    // defer-max: skip rescale while max grew by <= 8 (P bounded by 2^8)
    if (!__all(tm - m <= 8.0f)) {
      float mn = fmaxf(m, tm);
      float cf = exp2f(m - mn);
      m = mn;
      lsum *= cf;
      #pragma unroll
      for (int dt = 0; dt < 4; dt++) o[dt] *= cf;
    }
    float ps = 0.f;
    #pragma unroll
    for (int kt = 0; kt < 4; kt++) {
      float p0 = exp2f(st[kt][0] - m), p1 = exp2f(st[kt][1] - m);
      float p2 = exp2f(st[kt][2] - m), p3 = exp2f(st[kt][3] - m);
      ps += (p0 + p1) + (p2 + p3);
      uint2 pk;
      pk.x = (uint)bfh(p0) | ((uint)bfh(p1) << 16);
      pk.y = (uint)bfh(p2) | ((uint)bfh(p3) << 16);
      *(uint2*)&PT[w][q16][16 * kt + 4 * g] = pk;   // P[q16][k], k-contiguous
    }
    lsum += ps;

    // O^T += V^T P^T : A = VT from LDS, B = P row-read (b128)
    #pragma unroll
    for (int s = 0; s < 2; s++) {
      bf16x8 pf = *(const bf16x8*)&PT[w][q16][32 * s + 8 * g];
      #pragma unroll
      for (int dt = 0; dt < 4; dt++)
        o[dt] = __builtin_amdgcn_mfma_f32_16x16x32_bf16(
            *(const bf16x8*)&VTlds[dt * 16 + q16][32 * s + 8 * g],
            pf, o[dt], 0, 0, 0);
    }
    __syncthreads();
  }

  // reduce lsum across the 4 g-groups (k-partitions)
  lsum += __shfl_xor(lsum, 16, 64);
  lsum += __shfl_xor(lsum, 32, 64);

  // O^T store: lane holds O[q16][d=16dt+4g+r] -> OT[d][q] coalesced in q16
  float* OTp = OT + (size_t)split * 64 * SEQ;
  #pragma unroll
  for (int dt = 0; dt < 4; dt++)
    #pragma unroll
    for (int r = 0; r < 4; r++)
      OTp[(size_t)(16 * dt + 4 * g + r) * SEQ + qrow + q16] = o[dt][r];
  if (l < 16) {
    mpart[split * SEQ + qrow + l] = m;
    lpart[split * SEQ + qrow + l] = lsum;
  }
}

// ---------------- kernel 4: combine the KV-split partials -----------------
// OT layout [split][d][q]; 256 blocks x 32 q-rows, 8 d-groups of 8.
__global__ __launch_bounds__(256) void combine(
    const float* __restrict__ OT, const float* __restrict__ mpart,
    const float* __restrict__ lpart, float* __restrict__ out) {
  int t = threadIdx.x;
  int q = blockIdx.x * 32 + (t & 31);
  int dof = t >> 5;                      // 0..7, 8 d each
  float mm = -1e30f;
  #pragma unroll
  for (int s = 0; s < NSPLIT; s++) mm = fmaxf(mm, mpart[s * SEQ + q]);
  float ws[NSPLIT], den = 0.f;
  #pragma unroll
  for (int s = 0; s < NSPLIT; s++) {
    ws[s] = exp2f(mpart[s * SEQ + q] - mm);
    den += ws[s] * lpart[s * SEQ + q];
  }
  float rden = 1.0f / den;
  #pragma unroll
  for (int s = 0; s < NSPLIT; s++) ws[s] *= rden;
  #pragma unroll
  for (int k = 0; k < 8; k++) {
    int d = dof * 8 + k;
    float num = 0.f;
    #pragma unroll
    for (int s = 0; s < NSPLIT; s++)
      num += ws[s] * OT[(size_t)s * 64 * SEQ + (size_t)d * SEQ + q];
    out[(size_t)q * 64 + d] = num;
  }
}

extern "C" void kernel_launch(void* const* d_in, const int* in_sizes, int n_in,
                              void* d_out, int out_size, void* d_ws, size_t ws_size,
                              hipStream_t stream) {
  const float* x  = (const float*)d_in[0];
  const float* Wq = (const float*)d_in[1];
  const float* bq = (const float*)d_in[2];
  const float* Wk = (const float*)d_in[3];
  const float* bk = (const float*)d_in[4];
  const float* Wv = (const float*)d_in[5];
  const float* bv = (const float*)d_in[6];
  float* out = (float*)d_out;

  size_t off = 0;
  auto alloc = [&](size_t bytes) -> void* {
    void* p = (char*)d_ws + off;
    off += (bytes + 255) & ~(size_t)255;
    return p;
  };
  ushort* Wp    = (ushort*)alloc(192 * 512 * 2);
  float*  biasp = (float*) alloc(192 * 4);
  ushort* Qb    = (ushort*)alloc((size_t)SEQ * 64 * 2);
  ushort* Kb    = (ushort*)alloc((size_t)SEQ * 64 * 2);
  ushort* VTb   = (ushort*)alloc((size_t)64 * SEQ * 2);
  float*  OT    = (float*) alloc((size_t)NSPLIT * 64 * SEQ * 4);
  float*  mpart = (float*) alloc((size_t)NSPLIT * SEQ * 4);
  float*  lpart = (float*) alloc((size_t)NSPLIT * SEQ * 4);

  pack_w<<<(192 * 512 + 255) / 256, 256, 0, stream>>>(Wq, bq, Wk, bk, Wv, bv, Wp, biasp);
  qkv_proj<<<SEQ / 32, 512, 0, stream>>>(x, Wp, biasp, Qb, Kb, VTb);
  attn<<<(SEQ / QB) * NSPLIT, 512, 0, stream>>>(Qb, Kb, VTb, OT, mpart, lpart);
  combine<<<SEQ / 32, 256, 0, stream>>>(OT, mpart, lpart, out);
}